// Round 2
// baseline (561.170 us; speedup 1.0000x reference)
//
#include <hip/hip_runtime.h>
#include <math.h>

#define TSTEPS 200
#define NROTS  40      // 5*NQ*NL params per timestep circuit (2 layers)
#define DIM    16      // 2^NQ
#define BLK    256
#define DEG    3

__device__ __forceinline__ void fsc(float h, float& s, float& c) {
    s = __sinf(h); c = __cosf(h);
}

// Fused U = RZ(h3)*RY(h2)*RX(h1): only u00,u01 needed (u11=conj(u00), u10=-conj(u01)).
__device__ __forceinline__ void make_u(float h1, float h2, float h3,
                                       float& u00r, float& u00i, float& u01r, float& u01i) {
    float s1, c1, s2, c2, s3, c3;
    fsc(h1, s1, c1); fsc(h2, s2, c2); fsc(h3, s3, c3);
    float A = c1 * c2, Bv = s1 * s2, C = c1 * s2, D = s1 * c2;
    u00r =  c3 * A + s3 * Bv;
    u00i =  c3 * Bv - s3 * A;
    u01r = -(c3 * C + s3 * D);
    u01i =  s3 * C - c3 * D;
}

// V[0..15] = real amps, V[16..31] = imag amps. State bit for wire w is (8>>w).
template<int BIT>
__device__ __forceinline__ void g_u2(float* V, float u00r, float u00i, float u01r, float u01i) {
    #pragma unroll
    for (int p = 0; p < DIM; ++p) {
        if (p & BIT) continue;
        const int q = p | BIT;
        float a0r = V[p], a0i = V[16 + p], a1r = V[q], a1i = V[16 + q];
        V[p]      =  u00r * a0r - u00i * a0i + u01r * a1r - u01i * a1i;
        V[16 + p] =  u00r * a0i + u00i * a0r + u01r * a1i + u01i * a1r;
        V[q]      = -u01r * a0r - u01i * a0i + u00r * a1r + u00i * a1i;
        V[16 + q] = -u01r * a0i + u01i * a0r + u00r * a1i - u00i * a1r;
    }
}

template<int CBIT, int TBIT>
__device__ __forceinline__ void g_crx(float* V, float h) {
    float s, c; fsc(h, s, c);
    #pragma unroll
    for (int p = 0; p < DIM; ++p) {
        if (!(p & CBIT) || (p & TBIT)) continue;   // control=1, target=0 rows
        const int q = p | TBIT;
        float a0r = V[p], a0i = V[16 + p], a1r = V[q], a1i = V[16 + q];
        V[p]      = c * a0r + s * a1i;
        V[16 + p] = c * a0i - s * a1r;
        V[q]      = c * a1r + s * a0i;
        V[16 + q] = c * a1i - s * a0r;
    }
}

__device__ __forceinline__ void apply_layer_f(float* V, const float* pp) {
    float ur, ui, vr, vi;
    make_u(0.5f * pp[0], 0.5f * pp[1],  0.5f * pp[2],  ur, ui, vr, vi); g_u2<8>(V, ur, ui, vr, vi);
    make_u(0.5f * pp[3], 0.5f * pp[4],  0.5f * pp[5],  ur, ui, vr, vi); g_u2<4>(V, ur, ui, vr, vi);
    make_u(0.5f * pp[6], 0.5f * pp[7],  0.5f * pp[8],  ur, ui, vr, vi); g_u2<2>(V, ur, ui, vr, vi);
    make_u(0.5f * pp[9], 0.5f * pp[10], 0.5f * pp[11], ur, ui, vr, vi); g_u2<1>(V, ur, ui, vr, vi);
    g_crx<8, 4>(V, 0.5f * pp[12]);
    g_crx<4, 2>(V, 0.5f * pp[13]);
    g_crx<2, 1>(V, 0.5f * pp[14]);
    g_crx<1, 8>(V, 0.5f * pp[15]);
    g_crx<1, 2>(V, 0.5f * pp[16]);
    g_crx<2, 4>(V, 0.5f * pp[17]);
    g_crx<4, 8>(V, 0.5f * pp[18]);
    g_crx<8, 1>(V, 0.5f * pp[19]);
}

// One block per batch element. Thread t simulates timestep t (t>=200: coeff 0).
extern "C" __global__ void __launch_bounds__(BLK)
qac_kernel(const float* __restrict__ tp,    // (B, T, NROTS)
           const float* __restrict__ poly,  // (DEG+1,)
           const float* __restrict__ mixr,  // (T,)
           const float* __restrict__ mixi,  // (T,)
           const float* __restrict__ qff,   // (20,)
           float* __restrict__ out)         // (B, 12)
{
    __shared__ float sp[TSTEPS * NROTS];        // 32000 B staged params
    __shared__ float s_red[4][32];              // per-wave reduced vectors (value-indexed)
    __shared__ float s_wr[16], s_wi[16];        // work vector
    __shared__ float s_ar[16], s_ai[16];        // QSVT accumulator
    // total LDS = 32000 + 512 + 256 = 32768 B exactly -> 5 blocks/CU

    const int b    = blockIdx.x;
    const int tid  = threadIdx.x;
    const int lane = tid & 63;
    const int wv   = tid >> 6;

    // coalesced stage of this batch's 8000 params into LDS
    const float4* g4 = (const float4*)(tp + (size_t)b * (TSTEPS * NROTS));
    float4* s4 = (float4*)sp;
    for (int i = tid; i < TSTEPS * NROTS / 4; i += BLK) s4[i] = g4[i];

    if (tid < 16) {
        s_wr[tid] = (tid == 0) ? 1.f : 0.f; s_wi[tid] = 0.f;
        s_ar[tid] = (tid == 0) ? poly[0] : 0.f; s_ai[tid] = 0.f;
    }
    __syncthreads();

    float cr_ = 0.f, ci_ = 0.f;
    if (tid < TSTEPS) { cr_ = mixr[tid]; ci_ = mixi[tid]; }
    const float* myp = &sp[((tid < TSTEPS) ? tid : (TSTEPS - 1)) * NROTS];

    // reduce-scatter destination value index = bitrev5(lane)
    const int vidx = ((lane & 1) << 4) | ((lane & 2) << 2) | (lane & 4) |
                     ((lane & 8) >> 2) | ((lane & 16) >> 4);

    #pragma unroll 1
    for (int k = 1; k <= DEG; ++k) {
        float V[32];
        #pragma unroll
        for (int i = 0; i < 16; ++i) { V[i] = s_wr[i]; V[16 + i] = s_wi[i]; }

        // 2 ansatz layers; params loaded per layer as float4 from LDS
        #pragma unroll
        for (int L = 0; L < 2; ++L) {
            float P[20];
            const float4* p4 = (const float4*)(myp + 20 * L);
            #pragma unroll
            for (int j = 0; j < 5; ++j) {
                float4 f = p4[j];
                P[4 * j] = f.x; P[4 * j + 1] = f.y; P[4 * j + 2] = f.z; P[4 * j + 3] = f.w;
            }
            apply_layer_f(V, P);
        }

        // scale by this timestep's LCU coefficient (0 for lanes t>=200)
        #pragma unroll
        for (int i = 0; i < 16; ++i) {
            float r = V[i], im = V[16 + i];
            V[i]      = r * cr_ - im * ci_;
            V[16 + i] = r * ci_ + im * cr_;
        }

        // reduce-scatter butterfly: 5 halving steps over lane bits 0..4,
        // then cross-half add over bit 5. Lane ends with full 64-lane sum of value vidx.
        #pragma unroll
        for (int s = 0; s < 5; ++s) {
            const int half = 16 >> s;
            const bool hi = (lane >> s) & 1;
            #pragma unroll
            for (int j = 0; j < half; ++j) {
                float send = hi ? V[j] : V[j + half];
                float keep = hi ? V[j + half] : V[j];
                V[j] = keep + __shfl_xor(send, 1 << s, 64);
            }
        }
        float tot = V[0] + __shfl_xor(V[0], 32, 64);
        if (lane < 32) s_red[wv][vidx] = tot;   // vidx is a permutation of 0..31: conflict-free

        __syncthreads();
        if (tid < 32) {
            float r = s_red[0][tid] + s_red[1][tid] + s_red[2][tid] + s_red[3][tid];
            const float pk = poly[k];
            if (tid < 16) { s_wr[tid] = r;      s_ar[tid]      += pk * r; }
            else          { s_wi[tid - 16] = r; s_ai[tid - 16] += pk * r; }
        }
        __syncthreads();
    }

    // ---- finalize on wave 0, lane-per-amplitude (l = state index 0..15) ----
    if (tid < 16) {
        const int l = tid;
        float l1 = fabsf(poly[0]) + fabsf(poly[1]) + fabsf(poly[2]) + fabsf(poly[3]);
        float inv = 1.f / l1;
        float ar = s_ar[l] * inv, ai = s_ai[l] * inv;
        float n2 = ar * ar + ai * ai;
        #pragma unroll
        for (int o = 1; o < 16; o <<= 1) n2 += __shfl_xor(n2, o, 64);
        float sc = 1.f / (sqrtf(n2) + 1e-9f);
        ar *= sc; ai *= sc;

        float s, c, pr, pi, se, ce, t0;
        // qff ansatz, 1 layer: per-wire RX,RY,RZ
        #pragma unroll
        for (int w = 0; w < 4; ++w) {
            const int BIT = 8 >> w;
            // RX: a' = c*a - i*s*partner  (same formula both sides)
            fsc(0.5f * qff[3 * w + 0], s, c);
            pr = __shfl_xor(ar, BIT, 64); pi = __shfl_xor(ai, BIT, 64);
            t0 = c * ar + s * pi; ai = c * ai - s * pr; ar = t0;
            // RY: sign of s flips with target bit
            fsc(0.5f * qff[3 * w + 1], s, c);
            pr = __shfl_xor(ar, BIT, 64); pi = __shfl_xor(ai, BIT, 64);
            se = (l & BIT) ? s : -s;
            t0 = c * ar + se * pr; ai = c * ai + se * pi; ar = t0;
            // RZ: phase e^{±ih}, no shfl
            fsc(0.5f * qff[3 * w + 2], s, c);
            se = (l & BIT) ? s : -s;
            t0 = c * ar - se * ai; ai = c * ai + se * ar; ar = t0;
        }
        // CRX rings
        #define CRXF(CB, TB, hp) { fsc(0.5f * (hp), s, c);                        \
            pr = __shfl_xor(ar, TB, 64); pi = __shfl_xor(ai, TB, 64);             \
            ce = (l & CB) ? c : 1.f; se = (l & CB) ? s : 0.f;                     \
            t0 = ce * ar + se * pi; ai = ce * ai - se * pr; ar = t0; }
        CRXF(8, 4, qff[12]) CRXF(4, 2, qff[13]) CRXF(2, 1, qff[14]) CRXF(1, 8, qff[15])
        CRXF(1, 2, qff[16]) CRXF(2, 4, qff[17]) CRXF(4, 8, qff[18]) CRXF(8, 1, qff[19])
        #undef CRXF

        // expectation values
        float* o = out + (size_t)b * 12;
        #pragma unroll
        for (int w = 0; w < 4; ++w) {
            const int BIT = 8 >> w;
            pr = __shfl_xor(ar, BIT, 64); pi = __shfl_xor(ai, BIT, 64);
            float m = (l & BIT) ? 0.f : 1.f;
            float X = m * 2.f * (ar * pr + ai * pi);
            float Y = m * 2.f * (ar * pi - ai * pr);
            float Z = m * (ar * ar + ai * ai - pr * pr - pi * pi);
            #pragma unroll
            for (int of = 1; of < 16; of <<= 1) {
                X += __shfl_xor(X, of, 64);
                Y += __shfl_xor(Y, of, 64);
                Z += __shfl_xor(Z, of, 64);
            }
            if (l == 0) { o[w] = X; o[4 + w] = Y; o[8 + w] = Z; }
        }
    }
}

extern "C" void kernel_launch(void* const* d_in, const int* in_sizes, int n_in,
                              void* d_out, int out_size, void* d_ws, size_t ws_size,
                              hipStream_t stream) {
    const float* tp   = (const float*)d_in[0];
    const float* poly = (const float*)d_in[1];
    const float* mixr = (const float*)d_in[2];
    const float* mixi = (const float*)d_in[3];
    const float* qff  = (const float*)d_in[4];
    float* out = (float*)d_out;
    const int B = in_sizes[0] / (TSTEPS * NROTS);   // 2048
    qac_kernel<<<dim3(B), dim3(BLK), 0, stream>>>(tp, poly, mixr, mixi, qff, out);
}

// Round 3
// 206.774 us; speedup vs baseline: 2.7139x; 2.7139x over previous
//
#include <hip/hip_runtime.h>
#include <math.h>

#define TSTEPS 200
#define NROTS  40      // 5*NQ*NL params per timestep circuit (2 layers)
#define BLK    256
#define DEG    3

typedef float f2 __attribute__((ext_vector_type(2)));   // (re, im)

__device__ __forceinline__ void fsc(float h, float& s, float& c) {
    s = __sinf(h); c = __cosf(h);
}

__device__ __forceinline__ f2 crot(f2 a) { return (f2){-a.y, a.x}; }   // i*a

// Fused U = RZ(h3)*RY(h2)*RX(h1); only u00,u01 needed (u11=conj(u00), u10=-conj(u01)).
// Formulas verified correct in round 2.
__device__ __forceinline__ void make_u(float h1, float h2, float h3,
                                       float& u00r, float& u00i, float& u01r, float& u01i) {
    float s1, c1, s2, c2, s3, c3;
    fsc(h1, s1, c1); fsc(h2, s2, c2); fsc(h3, s3, c3);
    float A = c1 * c2, Bv = s1 * s2, C = c1 * s2, D = s1 * c2;
    u00r =  c3 * A + s3 * Bv;
    u00i =  c3 * Bv - s3 * A;
    u01r = -(c3 * C + s3 * D);
    u01i =  s3 * C - c3 * D;
}

// State: A[0..15] complex amplitudes; wire w <-> bit (8>>w).
template<int BIT>
__device__ __forceinline__ void g_u2(f2* A, float u00r, float u00i, float u01r, float u01i) {
    #pragma unroll
    for (int p = 0; p < 16; ++p) {
        if (p & BIT) continue;
        const int q = p | BIT;
        f2 a0 = A[p], a1 = A[q];
        f2 r0 = crot(a0), r1 = crot(a1);
        A[p] =  u00r * a0 + u00i * r0 + u01r * a1 + u01i * r1;
        A[q] =  u00r * a1 - u00i * r1 - u01r * a0 + u01i * r0;
    }
}

template<int CBIT, int TBIT>
__device__ __forceinline__ void g_crx(f2* A, float h) {
    float s, c; fsc(h, s, c);
    #pragma unroll
    for (int p = 0; p < 16; ++p) {
        if (!(p & CBIT) || (p & TBIT)) continue;   // control=1, target=0 rows
        const int q = p | TBIT;
        f2 a0 = A[p], a1 = A[q];
        A[p] = c * a0 - s * crot(a1);
        A[q] = c * a1 - s * crot(a0);
    }
}

// One ansatz layer; p4 points at this layer's 20 params (float4-aligned).
__device__ __forceinline__ void apply_layer_g(f2* A, const float4* p4) {
    float4 f0 = p4[0], f1 = p4[1], f2v = p4[2], f3 = p4[3], f4 = p4[4];
    float ur, ui, vr, vi;
    make_u(0.5f*f0.x, 0.5f*f0.y,  0.5f*f0.z,  ur, ui, vr, vi); g_u2<8>(A, ur, ui, vr, vi);
    make_u(0.5f*f0.w, 0.5f*f1.x,  0.5f*f1.y,  ur, ui, vr, vi); g_u2<4>(A, ur, ui, vr, vi);
    make_u(0.5f*f1.z, 0.5f*f1.w,  0.5f*f2v.x, ur, ui, vr, vi); g_u2<2>(A, ur, ui, vr, vi);
    make_u(0.5f*f2v.y, 0.5f*f2v.z, 0.5f*f2v.w, ur, ui, vr, vi); g_u2<1>(A, ur, ui, vr, vi);
    g_crx<8, 4>(A, 0.5f*f3.x);
    g_crx<4, 2>(A, 0.5f*f3.y);
    g_crx<2, 1>(A, 0.5f*f3.z);
    g_crx<1, 8>(A, 0.5f*f3.w);
    g_crx<1, 2>(A, 0.5f*f4.x);
    g_crx<2, 4>(A, 0.5f*f4.y);
    g_crx<4, 8>(A, 0.5f*f4.z);
    g_crx<8, 1>(A, 0.5f*f4.w);
}

// Reduce-scatter halving step: HALF and S are template constants -> all
// register-array indices compile-time (the round-2 failure mode removed).
template<int S, int HALF>
__device__ __forceinline__ void rstep(f2* A, int lane) {
    const bool hi = (lane >> S) & 1;
    #pragma unroll
    for (int j = 0; j < HALF; ++j) {
        f2 send = hi ? A[j] : A[j + HALF];
        f2 keep = hi ? A[j + HALF] : A[j];
        f2 got;
        got.x = __shfl_xor(send.x, 1 << S, 64);
        got.y = __shfl_xor(send.y, 1 << S, 64);
        A[j] = keep + got;
    }
}

// One block per batch element. Thread t simulates timestep t (t>=200: coeff 0).
extern "C" __global__ void __launch_bounds__(BLK, 4)
qac_kernel(const float* __restrict__ tp,    // (B, T, NROTS)
           const float* __restrict__ poly,  // (DEG+1,)
           const float* __restrict__ mixr,  // (T,)
           const float* __restrict__ mixi,  // (T,)
           const float* __restrict__ qff,   // (20,)
           float* __restrict__ out)         // (B, 12)
{
    __shared__ f2 s_red[4][16];   // per-wave reduced vectors
    __shared__ f2 s_w[16];        // work vector
    __shared__ f2 s_acc[16];      // QSVT accumulator

    const int b    = blockIdx.x;
    const int tid  = threadIdx.x;
    const int lane = tid & 63;
    const int wv   = tid >> 6;

    if (tid < 16) {
        s_w[tid]   = (f2){tid == 0 ? 1.f : 0.f, 0.f};
        s_acc[tid] = (f2){tid == 0 ? poly[0] : 0.f, 0.f};
    }
    __syncthreads();

    float cr_ = 0.f, ci_ = 0.f;
    if (tid < TSTEPS) { cr_ = mixr[tid]; ci_ = mixi[tid]; }
    const int mt = (tid < TSTEPS) ? tid : (TSTEPS - 1);
    const float4* p4 = (const float4*)(tp + (size_t)b * (TSTEPS * NROTS) + mt * NROTS);

    // reduce-scatter destination: value index bitrev4(lane&15)
    const int vidx = ((lane & 1) << 3) | ((lane & 2) << 1) | ((lane & 4) >> 1) | ((lane & 8) >> 3);

    for (int k = 1; k <= DEG; ++k) {
        f2 A[16];
        #pragma unroll
        for (int i = 0; i < 16; ++i) A[i] = s_w[i];

        apply_layer_g(A, p4);
        apply_layer_g(A, p4 + 5);

        // scale by this timestep's LCU coefficient (0 for lanes t>=200)
        #pragma unroll
        for (int i = 0; i < 16; ++i) A[i] = cr_ * A[i] + ci_ * crot(A[i]);

        // reduce-scatter over lane bits 0..3, then full adds over bits 4,5
        rstep<0, 8>(A, lane);
        rstep<1, 4>(A, lane);
        rstep<2, 2>(A, lane);
        rstep<3, 1>(A, lane);
        f2 tot = A[0];
        tot.x += __shfl_xor(tot.x, 16, 64); tot.y += __shfl_xor(tot.y, 16, 64);
        tot.x += __shfl_xor(tot.x, 32, 64); tot.y += __shfl_xor(tot.y, 32, 64);
        if (lane < 16) s_red[wv][vidx] = tot;

        __syncthreads();   // also orders A-loads of s_w before its update below
        if (tid < 16) {
            f2 r = s_red[0][tid] + s_red[1][tid] + s_red[2][tid] + s_red[3][tid];
            s_w[tid] = r;
            s_acc[tid] += poly[k] * r;
        }
        __syncthreads();
    }

    // ---- finalize on wave 0, lane-per-amplitude (verified in round 2) ----
    if (tid < 16) {
        const int l = tid;
        float l1 = fabsf(poly[0]) + fabsf(poly[1]) + fabsf(poly[2]) + fabsf(poly[3]);
        float inv = 1.f / l1;
        float ar = s_acc[l].x * inv, ai = s_acc[l].y * inv;
        float n2 = ar * ar + ai * ai;
        #pragma unroll
        for (int o = 1; o < 16; o <<= 1) n2 += __shfl_xor(n2, o, 64);
        float sc = 1.f / (sqrtf(n2) + 1e-9f);
        ar *= sc; ai *= sc;

        float s, c, pr, pi, se, ce, t0;
        #pragma unroll
        for (int w = 0; w < 4; ++w) {
            const int BIT = 8 >> w;
            fsc(0.5f * qff[3 * w + 0], s, c);            // RX
            pr = __shfl_xor(ar, BIT, 64); pi = __shfl_xor(ai, BIT, 64);
            t0 = c * ar + s * pi; ai = c * ai - s * pr; ar = t0;
            fsc(0.5f * qff[3 * w + 1], s, c);            // RY
            pr = __shfl_xor(ar, BIT, 64); pi = __shfl_xor(ai, BIT, 64);
            se = (l & BIT) ? s : -s;
            t0 = c * ar + se * pr; ai = c * ai + se * pi; ar = t0;
            fsc(0.5f * qff[3 * w + 2], s, c);            // RZ
            se = (l & BIT) ? s : -s;
            t0 = c * ar - se * ai; ai = c * ai + se * ar; ar = t0;
        }
        #define CRXF(CB, TB, hp) { fsc(0.5f * (hp), s, c);                        \
            pr = __shfl_xor(ar, TB, 64); pi = __shfl_xor(ai, TB, 64);             \
            ce = (l & CB) ? c : 1.f; se = (l & CB) ? s : 0.f;                     \
            t0 = ce * ar + se * pi; ai = ce * ai - se * pr; ar = t0; }
        CRXF(8, 4, qff[12]) CRXF(4, 2, qff[13]) CRXF(2, 1, qff[14]) CRXF(1, 8, qff[15])
        CRXF(1, 2, qff[16]) CRXF(2, 4, qff[17]) CRXF(4, 8, qff[18]) CRXF(8, 1, qff[19])
        #undef CRXF

        float* o = out + (size_t)b * 12;
        #pragma unroll
        for (int w = 0; w < 4; ++w) {
            const int BIT = 8 >> w;
            pr = __shfl_xor(ar, BIT, 64); pi = __shfl_xor(ai, BIT, 64);
            float m = (l & BIT) ? 0.f : 1.f;
            float X = m * 2.f * (ar * pr + ai * pi);
            float Y = m * 2.f * (ar * pi - ai * pr);
            float Z = m * (ar * ar + ai * ai - pr * pr - pi * pi);
            #pragma unroll
            for (int of = 1; of < 16; of <<= 1) {
                X += __shfl_xor(X, of, 64);
                Y += __shfl_xor(Y, of, 64);
                Z += __shfl_xor(Z, of, 64);
            }
            if (l == 0) { o[w] = X; o[4 + w] = Y; o[8 + w] = Z; }
        }
    }
}

extern "C" void kernel_launch(void* const* d_in, const int* in_sizes, int n_in,
                              void* d_out, int out_size, void* d_ws, size_t ws_size,
                              hipStream_t stream) {
    const float* tp   = (const float*)d_in[0];
    const float* poly = (const float*)d_in[1];
    const float* mixr = (const float*)d_in[2];
    const float* mixi = (const float*)d_in[3];
    const float* qff  = (const float*)d_in[4];
    float* out = (float*)d_out;
    const int B = in_sizes[0] / (TSTEPS * NROTS);   // 2048
    qac_kernel<<<dim3(B), dim3(BLK), 0, stream>>>(tp, poly, mixr, mixi, qff, out);
}

// Round 4
// 163.119 us; speedup vs baseline: 3.4402x; 1.2676x over previous
//
#include <hip/hip_runtime.h>
#include <math.h>

#define TSTEPS 200
#define NROTS  40      // 5*NQ*NL params per timestep circuit (2 layers)
#define BLK    256
#define DEG    3

typedef float f2 __attribute__((ext_vector_type(2)));   // (re, im)

__device__ __forceinline__ void fsc(float h, float& s, float& c) {
    s = __sinf(h); c = __cosf(h);
}

__device__ __forceinline__ f2 crot(f2 a) { return (f2){-a.y, a.x}; }   // i*a

// Fused U = RZ(h3)*RY(h2)*RX(h1); only u00,u01 needed (u11=conj(u00), u10=-conj(u01)).
// Verified rounds 2-3.
__device__ __forceinline__ void make_u(float h1, float h2, float h3, float* u) {
    float s1, c1, s2, c2, s3, c3;
    fsc(h1, s1, c1); fsc(h2, s2, c2); fsc(h3, s3, c3);
    float A = c1 * c2, Bv = s1 * s2, C = c1 * s2, D = s1 * c2;
    u[0] =  c3 * A + s3 * Bv;      // u00r
    u[1] =  c3 * Bv - s3 * A;      // u00i
    u[2] = -(c3 * C + s3 * D);     // u01r
    u[3] =  s3 * C - c3 * D;       // u01i
}

// State: A[0..15] complex amplitudes; wire w <-> bit (8>>w). Verified round 3.
template<int BIT>
__device__ __forceinline__ void g_u2(f2* A, const float* u) {
    const float u00r = u[0], u00i = u[1], u01r = u[2], u01i = u[3];
    #pragma unroll
    for (int p = 0; p < 16; ++p) {
        if (p & BIT) continue;
        const int q = p | BIT;
        f2 a0 = A[p], a1 = A[q];
        f2 r0 = crot(a0), r1 = crot(a1);
        A[p] =  u00r * a0 + u00i * r0 + u01r * a1 + u01i * r1;
        A[q] =  u00r * a1 - u00i * r1 - u01r * a0 + u01i * r0;
    }
}

template<int CBIT, int TBIT>
__device__ __forceinline__ void g_crx_pre(f2* A, float s, float c) {
    #pragma unroll
    for (int p = 0; p < 16; ++p) {
        if (!(p & CBIT) || (p & TBIT)) continue;   // control=1, target=0 rows
        const int q = p | TBIT;
        f2 a0 = A[p], a1 = A[q];
        A[p] = c * a0 - s * crot(a1);
        A[q] = c * a1 - s * crot(a0);
    }
}

// One layer from precomputed trig: u[4][4] fused-U per wire, cs[8][2] per CRX.
__device__ __forceinline__ void apply_layer_pre(f2* A, const float (&u)[4][4],
                                                const float (&cs)[8][2]) {
    g_u2<8>(A, u[0]); g_u2<4>(A, u[1]); g_u2<2>(A, u[2]); g_u2<1>(A, u[3]);
    g_crx_pre<8, 4>(A, cs[0][0], cs[0][1]);
    g_crx_pre<4, 2>(A, cs[1][0], cs[1][1]);
    g_crx_pre<2, 1>(A, cs[2][0], cs[2][1]);
    g_crx_pre<1, 8>(A, cs[3][0], cs[3][1]);
    g_crx_pre<1, 2>(A, cs[4][0], cs[4][1]);
    g_crx_pre<2, 4>(A, cs[5][0], cs[5][1]);
    g_crx_pre<4, 8>(A, cs[6][0], cs[6][1]);
    g_crx_pre<8, 1>(A, cs[7][0], cs[7][1]);
}

// Reduce-scatter halving step: all register indices compile-time. Verified round 3.
template<int S, int HALF>
__device__ __forceinline__ void rstep(f2* A, int lane) {
    const bool hi = (lane >> S) & 1;
    #pragma unroll
    for (int j = 0; j < HALF; ++j) {
        f2 send = hi ? A[j] : A[j + HALF];
        f2 keep = hi ? A[j + HALF] : A[j];
        f2 got;
        got.x = __shfl_xor(send.x, 1 << S, 64);
        got.y = __shfl_xor(send.y, 1 << S, 64);
        A[j] = keep + got;
    }
}

// One block per batch element. Thread t simulates timestep t (t>=200: coeff 0).
extern "C" __global__ void __launch_bounds__(BLK)
qac_kernel(const float* __restrict__ tp,    // (B, T, NROTS)
           const float* __restrict__ poly,  // (DEG+1,)
           const float* __restrict__ mixr,  // (T,)
           const float* __restrict__ mixi,  // (T,)
           const float* __restrict__ qff,   // (20,)
           float* __restrict__ out)         // (B, 12)
{
    __shared__ f2 s_red[4][16];   // per-wave reduced vectors
    __shared__ f2 s_w[16];        // work vector
    __shared__ f2 s_acc[16];      // QSVT accumulator

    const int b    = blockIdx.x;
    const int tid  = threadIdx.x;
    const int lane = tid & 63;
    const int wv   = tid >> 6;

    if (tid < 16) {
        s_w[tid]   = (f2){tid == 0 ? 1.f : 0.f, 0.f};
        s_acc[tid] = (f2){tid == 0 ? poly[0] : 0.f, 0.f};
    }

    float cr_ = 0.f, ci_ = 0.f;
    if (tid < TSTEPS) { cr_ = mixr[tid]; ci_ = mixi[tid]; }
    const int mt = (tid < TSTEPS) ? tid : (TSTEPS - 1);
    const float4* p4 = (const float4*)(tp + (size_t)b * (TSTEPS * NROTS) + mt * NROTS);

    // ---- hoist ALL trig out of the QSVT loop (params identical each pass) ----
    float tu[2][4][4];   // [layer][wire][u00r,u00i,u01r,u01i]
    float tc[2][8][2];   // [layer][crx gate][s,c]
    #pragma unroll
    for (int L = 0; L < 2; ++L) {
        float4 f0 = p4[5*L+0], f1 = p4[5*L+1], f2v = p4[5*L+2], f3 = p4[5*L+3], f4 = p4[5*L+4];
        make_u(0.5f*f0.x,  0.5f*f0.y,  0.5f*f0.z,  tu[L][0]);
        make_u(0.5f*f0.w,  0.5f*f1.x,  0.5f*f1.y,  tu[L][1]);
        make_u(0.5f*f1.z,  0.5f*f1.w,  0.5f*f2v.x, tu[L][2]);
        make_u(0.5f*f2v.y, 0.5f*f2v.z, 0.5f*f2v.w, tu[L][3]);
        fsc(0.5f*f3.x, tc[L][0][0], tc[L][0][1]);
        fsc(0.5f*f3.y, tc[L][1][0], tc[L][1][1]);
        fsc(0.5f*f3.z, tc[L][2][0], tc[L][2][1]);
        fsc(0.5f*f3.w, tc[L][3][0], tc[L][3][1]);
        fsc(0.5f*f4.x, tc[L][4][0], tc[L][4][1]);
        fsc(0.5f*f4.y, tc[L][5][0], tc[L][5][1]);
        fsc(0.5f*f4.z, tc[L][6][0], tc[L][6][1]);
        fsc(0.5f*f4.w, tc[L][7][0], tc[L][7][1]);
    }

    // reduce-scatter destination: value index bitrev4(lane&15)
    const int vidx = ((lane & 1) << 3) | ((lane & 2) << 1) | ((lane & 4) >> 1) | ((lane & 8) >> 3);

    __syncthreads();

    #pragma unroll 1
    for (int k = 1; k <= DEG; ++k) {
        f2 A[16];
        #pragma unroll
        for (int i = 0; i < 16; ++i) A[i] = s_w[i];

        apply_layer_pre(A, tu[0], tc[0]);
        apply_layer_pre(A, tu[1], tc[1]);

        // scale by this timestep's LCU coefficient (0 for lanes t>=200)
        #pragma unroll
        for (int i = 0; i < 16; ++i) A[i] = cr_ * A[i] + ci_ * crot(A[i]);

        // reduce-scatter over lane bits 0..3, then full adds over bits 4,5
        rstep<0, 8>(A, lane);
        rstep<1, 4>(A, lane);
        rstep<2, 2>(A, lane);
        rstep<3, 1>(A, lane);
        f2 tot = A[0];
        tot.x += __shfl_xor(tot.x, 16, 64); tot.y += __shfl_xor(tot.y, 16, 64);
        tot.x += __shfl_xor(tot.x, 32, 64); tot.y += __shfl_xor(tot.y, 32, 64);
        if (lane < 16) s_red[wv][vidx] = tot;

        __syncthreads();
        if (tid < 16) {
            f2 r = s_red[0][tid] + s_red[1][tid] + s_red[2][tid] + s_red[3][tid];
            s_w[tid] = r;
            s_acc[tid] += poly[k] * r;
        }
        __syncthreads();
    }

    // ---- finalize on wave 0, lane-per-amplitude (verified round 2) ----
    if (tid < 16) {
        const int l = tid;
        float l1 = fabsf(poly[0]) + fabsf(poly[1]) + fabsf(poly[2]) + fabsf(poly[3]);
        float inv = 1.f / l1;
        float ar = s_acc[l].x * inv, ai = s_acc[l].y * inv;
        float n2 = ar * ar + ai * ai;
        #pragma unroll
        for (int o = 1; o < 16; o <<= 1) n2 += __shfl_xor(n2, o, 64);
        float sc = 1.f / (sqrtf(n2) + 1e-9f);
        ar *= sc; ai *= sc;

        float s, c, pr, pi, se, ce, t0;
        #pragma unroll
        for (int w = 0; w < 4; ++w) {
            const int BIT = 8 >> w;
            fsc(0.5f * qff[3 * w + 0], s, c);            // RX
            pr = __shfl_xor(ar, BIT, 64); pi = __shfl_xor(ai, BIT, 64);
            t0 = c * ar + s * pi; ai = c * ai - s * pr; ar = t0;
            fsc(0.5f * qff[3 * w + 1], s, c);            // RY
            pr = __shfl_xor(ar, BIT, 64); pi = __shfl_xor(ai, BIT, 64);
            se = (l & BIT) ? s : -s;
            t0 = c * ar + se * pr; ai = c * ai + se * pi; ar = t0;
            fsc(0.5f * qff[3 * w + 2], s, c);            // RZ
            se = (l & BIT) ? s : -s;
            t0 = c * ar - se * ai; ai = c * ai + se * ar; ar = t0;
        }
        #define CRXF(CB, TB, hp) { fsc(0.5f * (hp), s, c);                        \
            pr = __shfl_xor(ar, TB, 64); pi = __shfl_xor(ai, TB, 64);             \
            ce = (l & CB) ? c : 1.f; se = (l & CB) ? s : 0.f;                     \
            t0 = ce * ar + se * pi; ai = ce * ai - se * pr; ar = t0; }
        CRXF(8, 4, qff[12]) CRXF(4, 2, qff[13]) CRXF(2, 1, qff[14]) CRXF(1, 8, qff[15])
        CRXF(1, 2, qff[16]) CRXF(2, 4, qff[17]) CRXF(4, 8, qff[18]) CRXF(8, 1, qff[19])
        #undef CRXF

        float* o = out + (size_t)b * 12;
        #pragma unroll
        for (int w = 0; w < 4; ++w) {
            const int BIT = 8 >> w;
            pr = __shfl_xor(ar, BIT, 64); pi = __shfl_xor(ai, BIT, 64);
            float m = (l & BIT) ? 0.f : 1.f;
            float X = m * 2.f * (ar * pr + ai * pi);
            float Y = m * 2.f * (ar * pi - ai * pr);
            float Z = m * (ar * ar + ai * ai - pr * pr - pi * pi);
            #pragma unroll
            for (int of = 1; of < 16; of <<= 1) {
                X += __shfl_xor(X, of, 64);
                Y += __shfl_xor(Y, of, 64);
                Z += __shfl_xor(Z, of, 64);
            }
            if (l == 0) { o[w] = X; o[4 + w] = Y; o[8 + w] = Z; }
        }
    }
}

extern "C" void kernel_launch(void* const* d_in, const int* in_sizes, int n_in,
                              void* d_out, int out_size, void* d_ws, size_t ws_size,
                              hipStream_t stream) {
    const float* tp   = (const float*)d_in[0];
    const float* poly = (const float*)d_in[1];
    const float* mixr = (const float*)d_in[2];
    const float* mixi = (const float*)d_in[3];
    const float* qff  = (const float*)d_in[4];
    float* out = (float*)d_out;
    const int B = in_sizes[0] / (TSTEPS * NROTS);   // 2048
    qac_kernel<<<dim3(B), dim3(BLK), 0, stream>>>(tp, poly, mixr, mixi, qff, out);
}

// Round 5
// 146.926 us; speedup vs baseline: 3.8194x; 1.1102x over previous
//
#include <hip/hip_runtime.h>
#include <math.h>

#define TSTEPS 200
#define NROTS  40      // 5*NQ*NL params per timestep circuit (2 layers)
#define BLK    256
#define DEG    3

__device__ __forceinline__ void fsc(float h, float& s, float& c) {
    s = __sinf(h); c = __cosf(h);
}

// Fused U = RZ(h3)*RY(h2)*RX(h1); only u00,u01 needed (u11=conj(u00), u10=-conj(u01)).
// Verified rounds 2-4.
__device__ __forceinline__ void make_u(float h1, float h2, float h3, float* u) {
    float s1, c1, s2, c2, s3, c3;
    fsc(h1, s1, c1); fsc(h2, s2, c2); fsc(h3, s3, c3);
    float A = c1 * c2, Bv = s1 * s2, C = c1 * s2, D = s1 * c2;
    u[0] =  c3 * A + s3 * Bv;      // u00r
    u[1] =  c3 * Bv - s3 * A;      // u00i
    u[2] = -(c3 * C + s3 * D);     // u01r
    u[3] =  s3 * C - c3 * D;       // u01i
}

// Planar state: V[0..15] = real amps, V[16..31] = imag. Wire w <-> bit (8>>w).
// Gate formulas verified in round 2. ALL V[] indices compile-time constants.
template<int BIT>
__device__ __forceinline__ void g_u2(float* V, const float* u) {
    const float u00r = u[0], u00i = u[1], u01r = u[2], u01i = u[3];
    #pragma unroll
    for (int p = 0; p < 16; ++p) {
        if (p & BIT) continue;
        const int q = p | BIT;
        float a0r = V[p], a0i = V[16 + p], a1r = V[q], a1i = V[16 + q];
        V[p]      =  u00r * a0r - u00i * a0i + u01r * a1r - u01i * a1i;
        V[16 + p] =  u00r * a0i + u00i * a0r + u01r * a1i + u01i * a1r;
        V[q]      = -u01r * a0r - u01i * a0i + u00r * a1r + u00i * a1i;
        V[16 + q] = -u01r * a0i + u01i * a0r + u00r * a1i - u00i * a1r;
    }
}

template<int CBIT, int TBIT>
__device__ __forceinline__ void g_crx_pre(float* V, float s, float c) {
    #pragma unroll
    for (int p = 0; p < 16; ++p) {
        if (!(p & CBIT) || (p & TBIT)) continue;   // control=1, target=0 rows
        const int q = p | TBIT;
        float a0r = V[p], a0i = V[16 + p], a1r = V[q], a1i = V[16 + q];
        V[p]      = c * a0r + s * a1i;
        V[16 + p] = c * a0i - s * a1r;
        V[q]      = c * a1r + s * a0i;
        V[16 + q] = c * a1i - s * a0r;
    }
}

__device__ __forceinline__ void apply_layer_pre(float* V, const float (&u)[4][4],
                                                const float (&cs)[8][2]) {
    g_u2<8>(V, u[0]); g_u2<4>(V, u[1]); g_u2<2>(V, u[2]); g_u2<1>(V, u[3]);
    g_crx_pre<8, 4>(V, cs[0][0], cs[0][1]);
    g_crx_pre<4, 2>(V, cs[1][0], cs[1][1]);
    g_crx_pre<2, 1>(V, cs[2][0], cs[2][1]);
    g_crx_pre<1, 8>(V, cs[3][0], cs[3][1]);
    g_crx_pre<1, 2>(V, cs[4][0], cs[4][1]);
    g_crx_pre<2, 4>(V, cs[5][0], cs[5][1]);
    g_crx_pre<4, 8>(V, cs[6][0], cs[6][1]);
    g_crx_pre<8, 1>(V, cs[7][0], cs[7][1]);
}

// Reduce-scatter halving step over the planar 32-value array. S and HALF are
// template constants -> every V[] index is compile-time (round-2 hazard removed).
template<int S, int HALF>
__device__ __forceinline__ void rstep(float* V, int lane) {
    const bool hi = (lane >> S) & 1;
    #pragma unroll
    for (int j = 0; j < HALF; ++j) {
        float send = hi ? V[j] : V[j + HALF];
        float keep = hi ? V[j + HALF] : V[j];
        V[j] = keep + __shfl_xor(send, 1 << S, 64);
    }
}

// One block per batch element. Thread t simulates timestep t (t>=200: coeff 0).
extern "C" __global__ void __launch_bounds__(BLK)
qac_kernel(const float* __restrict__ tp,    // (B, T, NROTS)
           const float* __restrict__ poly,  // (DEG+1,)
           const float* __restrict__ mixr,  // (T,)
           const float* __restrict__ mixi,  // (T,)
           const float* __restrict__ qff,   // (20,)
           float* __restrict__ out)         // (B, 12)
{
    __shared__ float s_red[4][32];   // per-wave reduced values (value-indexed)
    __shared__ float s_w[32];        // work vector  (0..15 re, 16..31 im)
    __shared__ float s_acc[32];      // QSVT accumulator, same layout

    const int b    = blockIdx.x;
    const int tid  = threadIdx.x;
    const int lane = tid & 63;
    const int wv   = tid >> 6;

    if (tid < 32) {
        s_w[tid]   = (tid == 0) ? 1.f : 0.f;
        s_acc[tid] = (tid == 0) ? poly[0] : 0.f;
    }

    float cr_ = 0.f, ci_ = 0.f;
    if (tid < TSTEPS) { cr_ = mixr[tid]; ci_ = mixi[tid]; }
    const int mt = (tid < TSTEPS) ? tid : (TSTEPS - 1);
    const float4* p4 = (const float4*)(tp + (size_t)b * (TSTEPS * NROTS) + mt * NROTS);

    // ---- hoist ALL trig out of the QSVT loop (params identical each pass) ----
    float tu[2][4][4];   // [layer][wire][u00r,u00i,u01r,u01i]
    float tc[2][8][2];   // [layer][crx gate][s,c]
    #pragma unroll
    for (int L = 0; L < 2; ++L) {
        float4 f0 = p4[5*L+0], f1 = p4[5*L+1], f2v = p4[5*L+2], f3 = p4[5*L+3], f4 = p4[5*L+4];
        make_u(0.5f*f0.x,  0.5f*f0.y,  0.5f*f0.z,  tu[L][0]);
        make_u(0.5f*f0.w,  0.5f*f1.x,  0.5f*f1.y,  tu[L][1]);
        make_u(0.5f*f1.z,  0.5f*f1.w,  0.5f*f2v.x, tu[L][2]);
        make_u(0.5f*f2v.y, 0.5f*f2v.z, 0.5f*f2v.w, tu[L][3]);
        fsc(0.5f*f3.x, tc[L][0][0], tc[L][0][1]);
        fsc(0.5f*f3.y, tc[L][1][0], tc[L][1][1]);
        fsc(0.5f*f3.z, tc[L][2][0], tc[L][2][1]);
        fsc(0.5f*f3.w, tc[L][3][0], tc[L][3][1]);
        fsc(0.5f*f4.x, tc[L][4][0], tc[L][4][1]);
        fsc(0.5f*f4.y, tc[L][5][0], tc[L][5][1]);
        fsc(0.5f*f4.z, tc[L][6][0], tc[L][6][1]);
        fsc(0.5f*f4.w, tc[L][7][0], tc[L][7][1]);
    }

    // reduce-scatter destination: value index bitrev5(lane&31) (verified round 2)
    const int vidx = ((lane & 1) << 4) | ((lane & 2) << 2) | (lane & 4) |
                     ((lane & 8) >> 2) | ((lane & 16) >> 4);

    __syncthreads();

    #pragma unroll 1
    for (int k = 1; k <= DEG; ++k) {
        float V[32];
        #pragma unroll
        for (int i = 0; i < 32; ++i) V[i] = s_w[i];

        apply_layer_pre(V, tu[0], tc[0]);
        apply_layer_pre(V, tu[1], tc[1]);

        // scale by this timestep's LCU coefficient (0 for lanes t>=200)
        #pragma unroll
        for (int i = 0; i < 16; ++i) {
            float r = V[i], im = V[16 + i];
            V[i]      = r * cr_ - im * ci_;
            V[16 + i] = r * ci_ + im * cr_;
        }

        // reduce-scatter over lane bits 0..4, then full add over bit 5
        rstep<0, 16>(V, lane);
        rstep<1, 8>(V, lane);
        rstep<2, 4>(V, lane);
        rstep<3, 2>(V, lane);
        rstep<4, 1>(V, lane);
        float tot = V[0] + __shfl_xor(V[0], 32, 64);
        if (lane < 32) s_red[wv][vidx] = tot;

        __syncthreads();
        if (tid < 32) {
            float r = s_red[0][tid] + s_red[1][tid] + s_red[2][tid] + s_red[3][tid];
            s_w[tid] = r;
            s_acc[tid] += poly[k] * r;
        }
        __syncthreads();
    }

    // ---- finalize on wave 0, lane-per-amplitude (verified round 2) ----
    if (tid < 16) {
        const int l = tid;
        float l1 = fabsf(poly[0]) + fabsf(poly[1]) + fabsf(poly[2]) + fabsf(poly[3]);
        float inv = 1.f / l1;
        float ar = s_acc[l] * inv, ai = s_acc[16 + l] * inv;
        float n2 = ar * ar + ai * ai;
        #pragma unroll
        for (int o = 1; o < 16; o <<= 1) n2 += __shfl_xor(n2, o, 64);
        float sc = 1.f / (sqrtf(n2) + 1e-9f);
        ar *= sc; ai *= sc;

        float s, c, pr, pi, se, ce, t0;
        #pragma unroll
        for (int w = 0; w < 4; ++w) {
            const int BIT = 8 >> w;
            fsc(0.5f * qff[3 * w + 0], s, c);            // RX
            pr = __shfl_xor(ar, BIT, 64); pi = __shfl_xor(ai, BIT, 64);
            t0 = c * ar + s * pi; ai = c * ai - s * pr; ar = t0;
            fsc(0.5f * qff[3 * w + 1], s, c);            // RY
            pr = __shfl_xor(ar, BIT, 64); pi = __shfl_xor(ai, BIT, 64);
            se = (l & BIT) ? s : -s;
            t0 = c * ar + se * pr; ai = c * ai + se * pi; ar = t0;
            fsc(0.5f * qff[3 * w + 2], s, c);            // RZ
            se = (l & BIT) ? s : -s;
            t0 = c * ar - se * ai; ai = c * ai + se * ar; ar = t0;
        }
        #define CRXF(CB, TB, hp) { fsc(0.5f * (hp), s, c);                        \
            pr = __shfl_xor(ar, TB, 64); pi = __shfl_xor(ai, TB, 64);             \
            ce = (l & CB) ? c : 1.f; se = (l & CB) ? s : 0.f;                     \
            t0 = ce * ar + se * pi; ai = ce * ai - se * pr; ar = t0; }
        CRXF(8, 4, qff[12]) CRXF(4, 2, qff[13]) CRXF(2, 1, qff[14]) CRXF(1, 8, qff[15])
        CRXF(1, 2, qff[16]) CRXF(2, 4, qff[17]) CRXF(4, 8, qff[18]) CRXF(8, 1, qff[19])
        #undef CRXF

        float* o = out + (size_t)b * 12;
        #pragma unroll
        for (int w = 0; w < 4; ++w) {
            const int BIT = 8 >> w;
            pr = __shfl_xor(ar, BIT, 64); pi = __shfl_xor(ai, BIT, 64);
            float m = (l & BIT) ? 0.f : 1.f;
            float X = m * 2.f * (ar * pr + ai * pi);
            float Y = m * 2.f * (ar * pi - ai * pr);
            float Z = m * (ar * ar + ai * ai - pr * pr - pi * pi);
            #pragma unroll
            for (int of = 1; of < 16; of <<= 1) {
                X += __shfl_xor(X, of, 64);
                Y += __shfl_xor(Y, of, 64);
                Z += __shfl_xor(Z, of, 64);
            }
            if (l == 0) { o[w] = X; o[4 + w] = Y; o[8 + w] = Z; }
        }
    }
}

extern "C" void kernel_launch(void* const* d_in, const int* in_sizes, int n_in,
                              void* d_out, int out_size, void* d_ws, size_t ws_size,
                              hipStream_t stream) {
    const float* tp   = (const float*)d_in[0];
    const float* poly = (const float*)d_in[1];
    const float* mixr = (const float*)d_in[2];
    const float* mixi = (const float*)d_in[3];
    const float* qff  = (const float*)d_in[4];
    float* out = (float*)d_out;
    const int B = in_sizes[0] / (TSTEPS * NROTS);   // 2048
    qac_kernel<<<dim3(B), dim3(BLK), 0, stream>>>(tp, poly, mixr, mixi, qff, out);
}